// Round 3
// baseline (5082.046 us; speedup 1.0000x reference)
//
#include <hip/hip_runtime.h>
#include <cstdint>
#include <cstddef>

// Problem constants
#define H_DIM   1024
#define T_STEPS 512           // L*N = 64*8 flattened time-major
#define VOCAB   32000
#define NBLK    128           // blocks in the fused scan
#define SLOT    2048          // floats per hcomb record: [y[t-1] ; h1[t-2]]
#define NSLOT   514           // slots 0..513
#define SENTU   0x40000000u   // 2.0f — unreachable: h = o*tanh(c) in [-1,1]
#define SPIN_CAP 5000000      // hang guard

__device__ __forceinline__ float gaload(const float* p) {
  return __hip_atomic_load(const_cast<float*>(p), __ATOMIC_RELAXED, __HIP_MEMORY_SCOPE_AGENT);
}
__device__ __forceinline__ void gastore(float* p, float v) {
  __hip_atomic_store(p, v, __ATOMIC_RELAXED, __HIP_MEMORY_SCOPE_AGENT);
}
__device__ __forceinline__ float sigmoid_f(float v) { return 1.f / (1.f + expf(-v)); }

// ---------------------------------------------------------------------------
// init: hcomb slot 0 = zeros (initial states), slots 1..513 = sentinel 2.0f.
// xmap[t] = x[n,l] time-major gather map.
// ---------------------------------------------------------------------------
__global__ void init_ws_k(const int* __restrict__ x,
                          float* __restrict__ hcomb, int* __restrict__ xmap)
{
  int tid = blockIdx.x * blockDim.x + threadIdx.x;
  int nt  = gridDim.x * blockDim.x;
  const float sent = __uint_as_float(SENTU);
  for (int i = tid; i < NSLOT * SLOT; i += nt)
    hcomb[i] = (i < SLOT) ? 0.f : sent;
  for (int t = tid; t < T_STEPS; t += nt) xmap[t] = x[(t & 7) * 64 + (t >> 3)];
}

// ---------------------------------------------------------------------------
// fp32 GEMM  C[M,N] = A[M,K] @ B[N,K]^T + bias0 + bias1.
// If A==null, row t of A is gathered as emb[xmap[t]].
// 128x128 tile, BK=16, 256 threads, 8x8 per-thread microtile.
// ---------------------------------------------------------------------------
#define BM 128
#define BN 128
#define BKD 16

__global__ __launch_bounds__(256) void gemm_atb_k(
    const float* __restrict__ A, const float* __restrict__ emb,
    const int* __restrict__ xmap,
    const float* __restrict__ B,
    const float* __restrict__ bias0, const float* __restrict__ bias1,
    float* __restrict__ C, int M, int N, int K)
{
  __shared__ __align__(16) float As[BKD][BM + 4];
  __shared__ __align__(16) float Bs[BKD][BN + 4];
  const int tid = threadIdx.x;
  const int tx = tid & 15, ty = tid >> 4;
  const int m0 = blockIdx.y * BM, n0 = blockIdx.x * BN;
  const int lr = tid >> 1;           // 0..127: row within tile
  const int lk = (tid & 1) * 8;      // 0 or 8: k sub-chunk
  const float* arow = A ? (A + (size_t)(m0 + lr) * K)
                        : (emb + (size_t)xmap[m0 + lr] * K);
  const float* brow = B + (size_t)(n0 + lr) * K;

  float acc[8][8];
  #pragma unroll
  for (int i = 0; i < 8; ++i)
    #pragma unroll
    for (int j = 0; j < 8; ++j) acc[i][j] = 0.f;

  for (int k0 = 0; k0 < K; k0 += BKD) {
    float4 a0 = *(const float4*)(arow + k0 + lk);
    float4 a1 = *(const float4*)(arow + k0 + lk + 4);
    float4 b0 = *(const float4*)(brow + k0 + lk);
    float4 b1 = *(const float4*)(brow + k0 + lk + 4);
    __syncthreads();   // protect previous iteration's LDS reads
    As[lk+0][lr]=a0.x; As[lk+1][lr]=a0.y; As[lk+2][lr]=a0.z; As[lk+3][lr]=a0.w;
    As[lk+4][lr]=a1.x; As[lk+5][lr]=a1.y; As[lk+6][lr]=a1.z; As[lk+7][lr]=a1.w;
    Bs[lk+0][lr]=b0.x; Bs[lk+1][lr]=b0.y; Bs[lk+2][lr]=b0.z; Bs[lk+3][lr]=b0.w;
    Bs[lk+4][lr]=b1.x; Bs[lk+5][lr]=b1.y; Bs[lk+6][lr]=b1.z; Bs[lk+7][lr]=b1.w;
    __syncthreads();
    #pragma unroll
    for (int kk = 0; kk < BKD; ++kk) {
      float4 av0 = *(const float4*)&As[kk][ty*8];
      float4 av1 = *(const float4*)&As[kk][ty*8+4];
      float4 bv0 = *(const float4*)&Bs[kk][tx*8];
      float4 bv1 = *(const float4*)&Bs[kk][tx*8+4];
      float av[8] = {av0.x,av0.y,av0.z,av0.w,av1.x,av1.y,av1.z,av1.w};
      float bv[8] = {bv0.x,bv0.y,bv0.z,bv0.w,bv1.x,bv1.y,bv1.z,bv1.w};
      #pragma unroll
      for (int i = 0; i < 8; ++i)
        #pragma unroll
        for (int j = 0; j < 8; ++j) acc[i][j] += av[i] * bv[j];
    }
  }
  float bvp[8];
  #pragma unroll
  for (int j = 0; j < 8; ++j) {
    int n = n0 + tx*8 + j;
    float s = 0.f;
    if (bias0) s += bias0[n];
    if (bias1) s += bias1[n];
    bvp[j] = s;
  }
  #pragma unroll
  for (int i = 0; i < 8; ++i) {
    int m = m0 + ty*8 + i;
    float* crow = C + (size_t)m * N + n0 + tx*8;
    float4 o0, o1;
    o0.x=acc[i][0]+bvp[0]; o0.y=acc[i][1]+bvp[1]; o0.z=acc[i][2]+bvp[2]; o0.w=acc[i][3]+bvp[3];
    o1.x=acc[i][4]+bvp[4]; o1.y=acc[i][5]+bvp[5]; o1.z=acc[i][6]+bvp[6]; o1.w=acc[i][7]+bvp[7];
    *(float4*)crow = o0;
    *(float4*)(crow + 4) = o1;
  }
}

// ---------------------------------------------------------------------------
// Fused persistent 2-layer LSTM scan. 128 blocks x 768 threads (12 waves,
// 3/SIMD). Block b owns hidden units [8b,8b+8) of BOTH layers.
// Tick t (0..512): layer0 step t AND layer1 step t-1, both consuming only
// hcomb[t] = [y[t-1](1024) ; h1[t-2](1024)]; emits its 16 floats of
// hcomb[t+1]. Sync = sentinel-in-data: slots pre-filled with 2.0f; the
// arriving h values ARE the ready flags (h in [-1,1], 2.0 unreachable).
// No flags, no fences, no RMW — round 1/2 evidence: those legs cost ~2/3 of
// the step chain.
// Waves 0-3: L0 gate w (8 rows x K=1024, 128 wVGPR/lane).
// Waves 4-11: L1 gate (w-4)>>1, K-half (w-4)&1 (8 rows x 1024, 128 wVGPR).
// ---------------------------------------------------------------------------
__global__ __launch_bounds__(768, 3) void lstm_seq_k(
    const float* __restrict__ Whh0,
    const float* __restrict__ Wih1,
    const float* __restrict__ Whh1,
    const float* __restrict__ bih1,
    const float* __restrict__ bhh1,
    const float* __restrict__ G0,
    float* __restrict__ hcomb,
    float* __restrict__ h1out,       // (512,1024) compact, FC-GEMM input
    float* __restrict__ out_hc)      // h(2x1024) then c(2x1024)
{
  const int b     = blockIdx.x;
  const int jbase = b * 8;
  const int tid   = threadIdx.x;
  const int w     = tid >> 6;      // 0..11
  const int lane  = tid & 63;

  __shared__ __align__(16) float hbuf[SLOT];
  __shared__ float gbuf[12][8];
  __shared__ float cb0[8], cb1[8];
  if (tid < 8) { cb0[tid] = 0.f; cb1[tid] = 0.f; }

  // ---- persistent weights: 8 rows x 16 k-elems per lane, k = q*256+lane*4 ----
  float wr[8][16];
  int xoff;                        // LDS read base for this wave's k-range
  {
    const float* base;
    int rowbase;
    if (w < 4) { base = Whh0; rowbase = w * 1024; xoff = 0; }
    else {
      int g = (w - 4) >> 1, kh = (w - 4) & 1;
      base = kh ? Whh1 : Wih1;
      rowbase = g * 1024;
      xoff = kh * 1024;
    }
    #pragma unroll
    for (int j = 0; j < 8; ++j) {
      const float* p = base + (size_t)(rowbase + jbase + j) * 1024 + lane * 4;
      #pragma unroll
      for (int q = 0; q < 4; ++q) {
        float4 v = *(const float4*)(p + q * 256);
        wr[j][q*4+0]=v.x; wr[j][q*4+1]=v.y; wr[j][q*4+2]=v.z; wr[j][q*4+3]=v.w;
      }
    }
  }
  // L1 biases for epilogue threads 8..15
  float bi1[4] = {0.f, 0.f, 0.f, 0.f};
  if (tid >= 8 && tid < 16) {
    int j = jbase + (tid - 8);
    #pragma unroll
    for (int g = 0; g < 4; ++g) bi1[g] = bih1[g*1024 + j] + bhh1[g*1024 + j];
  }
  __syncthreads();

  for (int t = 0; t <= T_STEPS; ++t) {
    // ---- poll slot t: 512 pollers x 4 words; data IS the flag ----
    if (tid < 512) {
      const float* p = hcomb + (size_t)t * SLOT + tid * 4;
      float4 v;
      int sp = 0;
      for (;;) {
        v.x = gaload(p+0); v.y = gaload(p+1); v.z = gaload(p+2); v.w = gaload(p+3);
        if (__float_as_uint(v.x) != SENTU && __float_as_uint(v.y) != SENTU &&
            __float_as_uint(v.z) != SENTU && __float_as_uint(v.w) != SENTU) break;
        __builtin_amdgcn_s_sleep(1);
        if (++sp > SPIN_CAP) break;
      }
      *(float4*)&hbuf[tid * 4] = v;
    }
    // G0[t] prefetch (independent; latency hides under poll tail + matvec)
    float g_i = 0.f, g_f = 0.f, g_g = 0.f, g_o = 0.f;
    if (tid < 8 && t < T_STEPS) {
      const float* g0 = G0 + (size_t)t * 4096 + jbase + tid;
      g_i = g0[0]; g_f = g0[1024]; g_g = g0[2048]; g_o = g0[3072];
    }
    __syncthreads();

    // ---- matvec: 8 rows x 64 k-elems per lane ----
    float4 xv[4];
    #pragma unroll
    for (int q = 0; q < 4; ++q)
      xv[q] = *(const float4*)&hbuf[xoff + q * 256 + lane * 4];
    float acc[8];
    #pragma unroll
    for (int j = 0; j < 8; ++j) {
      float s = 0.f;
      #pragma unroll
      for (int q = 0; q < 4; ++q)
        s += wr[j][q*4+0]*xv[q].x + wr[j][q*4+1]*xv[q].y +
             wr[j][q*4+2]*xv[q].z + wr[j][q*4+3]*xv[q].w;
      acc[j] = s;
    }
    #pragma unroll
    for (int j = 0; j < 8; ++j)
      #pragma unroll
      for (int msk = 1; msk < 64; msk <<= 1)
        acc[j] += __shfl_xor(acc[j], msk, 64);
    if (lane == 0) {
      #pragma unroll
      for (int j = 0; j < 8; ++j) gbuf[w][j] = acc[j];
    }
    __syncthreads();

    // ---- epilogue ----
    if (tid < 8) {                       // layer 0, step t
      if (t < T_STEPS) {
        const int j = tid;
        float iv = sigmoid_f(gbuf[0][j] + g_i);
        float fv = sigmoid_f(gbuf[1][j] + g_f);
        float gv = tanhf   (gbuf[2][j] + g_g);
        float ov = sigmoid_f(gbuf[3][j] + g_o);
        float c  = fv * cb0[j] + iv * gv;
        cb0[j]   = c;
        float h  = ov * tanhf(c);
        gastore(&hcomb[(size_t)(t+1) * SLOT + jbase + j], h);
        if (t == T_STEPS - 1) { out_hc[jbase + j] = h; out_hc[2048 + jbase + j] = c; }
      }
    } else if (tid < 16) {               // layer 1, step t-1
      const int j = tid - 8;
      float h = 0.f, c = 0.f;
      if (t > 0) {
        float iv = sigmoid_f(gbuf[4][j]  + gbuf[5][j]  + bi1[0]);
        float fv = sigmoid_f(gbuf[6][j]  + gbuf[7][j]  + bi1[1]);
        float gv = tanhf   (gbuf[8][j]  + gbuf[9][j]  + bi1[2]);
        float ov = sigmoid_f(gbuf[10][j] + gbuf[11][j] + bi1[3]);
        c = fv * cb1[j] + iv * gv;
        cb1[j] = c;
        h = ov * tanhf(c);
        h1out[(size_t)(t-1) * 1024 + jbase + j] = h;   // kernel-boundary visibility
      }
      gastore(&hcomb[(size_t)(t+1) * SLOT + 1024 + jbase + j], h);
      if (t == T_STEPS) { out_hc[1024 + jbase + j] = h; out_hc[3072 + jbase + j] = c; }
    }
    // No third barrier needed: next tick's hbuf writes are fenced from this
    // tick's hbuf reads by the post-matvec barrier; gbuf rewrite is fenced by
    // next tick's post-poll barrier.
  }
}

// ---------------------------------------------------------------------------
extern "C" void kernel_launch(void* const* d_in, const int* in_sizes, int n_in,
                              void* d_out, int out_size, void* d_ws, size_t ws_size,
                              hipStream_t stream)
{
  (void)in_sizes; (void)n_in; (void)out_size; (void)ws_size;
  const int*   x    = (const int*)  d_in[0];
  const float* emb  = (const float*)d_in[1];
  const float* W_ih = (const float*)d_in[2];   // (2, 4096, 1024)
  const float* W_hh = (const float*)d_in[3];
  const float* b_ih = (const float*)d_in[4];   // (2, 4096)
  const float* b_hh = (const float*)d_in[5];
  const float* W_fc = (const float*)d_in[6];   // (32000, 1024)
  const float* b_fc = (const float*)d_in[7];
  float* out = (float*)d_out;                  // scores(512x32000) | h(2x1024) | c(2x1024)

  // workspace layout (floats); ~14.6 MB total
  float* ws    = (float*)d_ws;
  float* G0    = ws;                                         // 512*4096
  float* hcomb = G0    + (size_t)T_STEPS * 4096;             // 514*2048
  float* h1out = hcomb + (size_t)NSLOT * SLOT;               // 512*1024
  int*   xmap  = (int*)(h1out + (size_t)T_STEPS * H_DIM);    // 512 ints

  init_ws_k<<<256, 256, 0, stream>>>(x, hcomb, xmap);

  // G0[t,:] = W_ih0 @ emb[x_t] + b_ih0 + b_hh0   (512 x 4096)
  gemm_atb_k<<<dim3(4096 / BN, T_STEPS / BM), 256, 0, stream>>>(
      nullptr, emb, xmap, W_ih, b_ih, b_hh, G0, T_STEPS, 4096, 1024);

  // fused sequential scan (both layers, one sync domain, sentinel signaling)
  lstm_seq_k<<<NBLK, 768, 0, stream>>>(
      W_hh, W_ih + (size_t)4096 * 1024, W_hh + (size_t)4096 * 1024,
      b_ih + 4096, b_hh + 4096, G0, hcomb, h1out,
      out + (size_t)T_STEPS * VOCAB);

  // scores = outs @ W_fc^T + b_fc
  gemm_atb_k<<<dim3(VOCAB / BN, T_STEPS / BM), 256, 0, stream>>>(
      h1out, nullptr, nullptr, W_fc, b_fc, nullptr, out, T_STEPS, VOCAB, 1024);
}

// Round 4
// 2533.725 us; speedup vs baseline: 2.0058x; 2.0058x over previous
//
#include <hip/hip_runtime.h>
#include <cstdint>
#include <cstddef>

// Problem constants
#define H_DIM   1024
#define T_STEPS 512           // L*N = 64*8 flattened time-major
#define VOCAB   32000
#define SENTU   0x40000000u   // 2.0f — unreachable: h = o*tanh(c) in [-1,1]
#define SPIN_CAP 5000000      // hang guard

__device__ __forceinline__ float gaload(const float* p) {
  return __hip_atomic_load(const_cast<float*>(p), __ATOMIC_RELAXED, __HIP_MEMORY_SCOPE_AGENT);
}
__device__ __forceinline__ void gastore(float* p, float v) {
  __hip_atomic_store(p, v, __ATOMIC_RELAXED, __HIP_MEMORY_SCOPE_AGENT);
}
__device__ __forceinline__ float sigmoid_f(float v) { return 1.f / (1.f + expf(-v)); }

// ---------------------------------------------------------------------------
// init: h0h/h1h slot 0 = zeros (initial state), slots 1..512 = sentinel.
// xmap[t] = x[n,l] time-major gather map.
// ---------------------------------------------------------------------------
__global__ void init_ws_k(const int* __restrict__ x,
                          float* __restrict__ h0h, float* __restrict__ h1h,
                          int* __restrict__ xmap)
{
  int tid = blockIdx.x * blockDim.x + threadIdx.x;
  int nt  = gridDim.x * blockDim.x;
  const float sent = __uint_as_float(SENTU);
  for (int i = tid; i < (T_STEPS + 1) * H_DIM; i += nt) {
    float v = (i < H_DIM) ? 0.f : sent;
    h0h[i] = v; h1h[i] = v;
  }
  for (int t = tid; t < T_STEPS; t += nt) xmap[t] = x[(t & 7) * 64 + (t >> 3)];
}

// ---------------------------------------------------------------------------
// fp32 GEMM  C[M,N] = A[M,K] @ B[N,K]^T + bias0 + bias1.
// If A==null, row t of A is gathered as emb[xmap[t]].
// 128x128 tile, BK=16, 256 threads, 8x8 per-thread microtile.
// ---------------------------------------------------------------------------
#define BM 128
#define BN 128
#define BKD 16

__global__ __launch_bounds__(256) void gemm_atb_k(
    const float* __restrict__ A, const float* __restrict__ emb,
    const int* __restrict__ xmap,
    const float* __restrict__ B,
    const float* __restrict__ bias0, const float* __restrict__ bias1,
    float* __restrict__ C, int M, int N, int K)
{
  __shared__ __align__(16) float As[BKD][BM + 4];
  __shared__ __align__(16) float Bs[BKD][BN + 4];
  const int tid = threadIdx.x;
  const int tx = tid & 15, ty = tid >> 4;
  const int m0 = blockIdx.y * BM, n0 = blockIdx.x * BN;
  const int lr = tid >> 1;           // 0..127: row within tile
  const int lk = (tid & 1) * 8;      // 0 or 8: k sub-chunk
  const float* arow = A ? (A + (size_t)(m0 + lr) * K)
                        : (emb + (size_t)xmap[m0 + lr] * K);
  const float* brow = B + (size_t)(n0 + lr) * K;

  float acc[8][8];
  #pragma unroll
  for (int i = 0; i < 8; ++i)
    #pragma unroll
    for (int j = 0; j < 8; ++j) acc[i][j] = 0.f;

  for (int k0 = 0; k0 < K; k0 += BKD) {
    float4 a0 = *(const float4*)(arow + k0 + lk);
    float4 a1 = *(const float4*)(arow + k0 + lk + 4);
    float4 b0 = *(const float4*)(brow + k0 + lk);
    float4 b1 = *(const float4*)(brow + k0 + lk + 4);
    __syncthreads();   // protect previous iteration's LDS reads
    As[lk+0][lr]=a0.x; As[lk+1][lr]=a0.y; As[lk+2][lr]=a0.z; As[lk+3][lr]=a0.w;
    As[lk+4][lr]=a1.x; As[lk+5][lr]=a1.y; As[lk+6][lr]=a1.z; As[lk+7][lr]=a1.w;
    Bs[lk+0][lr]=b0.x; Bs[lk+1][lr]=b0.y; Bs[lk+2][lr]=b0.z; Bs[lk+3][lr]=b0.w;
    Bs[lk+4][lr]=b1.x; Bs[lk+5][lr]=b1.y; Bs[lk+6][lr]=b1.z; Bs[lk+7][lr]=b1.w;
    __syncthreads();
    #pragma unroll
    for (int kk = 0; kk < BKD; ++kk) {
      float4 av0 = *(const float4*)&As[kk][ty*8];
      float4 av1 = *(const float4*)&As[kk][ty*8+4];
      float4 bv0 = *(const float4*)&Bs[kk][tx*8];
      float4 bv1 = *(const float4*)&Bs[kk][tx*8+4];
      float av[8] = {av0.x,av0.y,av0.z,av0.w,av1.x,av1.y,av1.z,av1.w};
      float bv[8] = {bv0.x,bv0.y,bv0.z,bv0.w,bv1.x,bv1.y,bv1.z,bv1.w};
      #pragma unroll
      for (int i = 0; i < 8; ++i)
        #pragma unroll
        for (int j = 0; j < 8; ++j) acc[i][j] += av[i] * bv[j];
    }
  }
  float bvp[8];
  #pragma unroll
  for (int j = 0; j < 8; ++j) {
    int n = n0 + tx*8 + j;
    float s = 0.f;
    if (bias0) s += bias0[n];
    if (bias1) s += bias1[n];
    bvp[j] = s;
  }
  #pragma unroll
  for (int i = 0; i < 8; ++i) {
    int m = m0 + ty*8 + i;
    float* crow = C + (size_t)m * N + n0 + tx*8;
    float4 o0, o1;
    o0.x=acc[i][0]+bvp[0]; o0.y=acc[i][1]+bvp[1]; o0.z=acc[i][2]+bvp[2]; o0.w=acc[i][3]+bvp[3];
    o1.x=acc[i][4]+bvp[4]; o1.y=acc[i][5]+bvp[5]; o1.z=acc[i][6]+bvp[6]; o1.w=acc[i][7]+bvp[7];
    *(float4*)crow = o0;
    *(float4*)(crow + 4) = o1;
  }
}

// ---------------------------------------------------------------------------
// Persistent sequential LSTM scan. 256 blocks x 512 threads (8 waves, 2/SIMD,
// __launch_bounds__(512,2) -> 256-VGPR cap; round 3 post-mortem: 12-wave
// variant spilled weights to scratch, VGPR_Count=84, +35MB fetch).
// Blocks 0..127: layer 0. Blocks 128..255: layer 1 (lags one step).
// Block owns hidden units [8b, 8b+8) + their c. Wave w = (gate w>>1,
// K-half w&1): L0 wr[8][8]=64 VGPR, L1 wr[8][16]=128 VGPR — both resident.
//
// Sync = sentinel-in-data (round 3, correctness-proven): h histories
// pre-filled with 2.0f (h in [-1,1] can't produce it); consumers poll the
// data words directly. No flags, no RMW, no fences — the arriving store IS
// the signal. Hot-spin 16 iters then s_sleep(1) to limit L3 poll traffic.
// ---------------------------------------------------------------------------
__global__ __launch_bounds__(512, 2) void lstm_seq_k(
    const float* __restrict__ Whh0,
    const float* __restrict__ Wih1,
    const float* __restrict__ Whh1,
    const float* __restrict__ bih1,
    const float* __restrict__ bhh1,
    const float* __restrict__ G0,
    float* __restrict__ h0h, float* __restrict__ h1h,   // (T+1) x 1024, sentinel
    float* __restrict__ h1out,                          // (512,1024) FC input
    float* __restrict__ out_hc)                         // h(2x1024) then c(2x1024)
{
  const int layer = blockIdx.x >> 7;
  const int b     = blockIdx.x & 127;
  const int jbase = b * 8;
  const int tid   = threadIdx.x;
  const int w     = tid >> 6;      // 0..7
  const int g     = w >> 1;        // gate i,f,g,o
  const int hh    = w & 1;         // k-half
  const int lane  = tid & 63;

  __shared__ __align__(16) float hbuf[2048];
  __shared__ float gbuf[8][8];
  __shared__ float cbuf[8];
  if (tid < 8) cbuf[tid] = 0.f;

  if (layer == 0) {
    // ---- L0: K=1024; wave covers k in [hh*512, hh*512+512); 64 wVGPR ----
    float wr[8][8];
    #pragma unroll
    for (int j = 0; j < 8; ++j) {
      const float* p = Whh0 + (size_t)(g*1024 + jbase + j) * 1024 + hh*512 + lane*4;
      #pragma unroll
      for (int q = 0; q < 2; ++q) {
        float4 v = *(const float4*)(p + q*256);
        wr[j][q*4+0]=v.x; wr[j][q*4+1]=v.y; wr[j][q*4+2]=v.z; wr[j][q*4+3]=v.w;
      }
    }
    __syncthreads();
    for (int t = 0; t < T_STEPS; ++t) {
      // G0 prefetch (independent of poll)
      float g0v[4] = {0.f,0.f,0.f,0.f};
      if (tid < 8) {
        const float* g0 = G0 + (size_t)t*4096 + jbase + tid;
        #pragma unroll
        for (int q = 0; q < 4; ++q) g0v[q] = g0[q*1024];
      }
      if (tid < 256) {        // poll+stage h0h[t]: data IS the flag
        const float* p = h0h + (size_t)t * H_DIM + tid*4;
        float4 v; int sp = 0;
        for (;;) {
          v.x = gaload(p+0); v.y = gaload(p+1); v.z = gaload(p+2); v.w = gaload(p+3);
          if (__float_as_uint(v.x) != SENTU && __float_as_uint(v.y) != SENTU &&
              __float_as_uint(v.z) != SENTU && __float_as_uint(v.w) != SENTU) break;
          if (++sp > 16) __builtin_amdgcn_s_sleep(1);
          if (sp > SPIN_CAP) break;
        }
        *(float4*)&hbuf[tid*4] = v;
      }
      __syncthreads();
      float acc[8];
      {
        float4 xv0 = *(const float4*)&hbuf[hh*512 + lane*4];
        float4 xv1 = *(const float4*)&hbuf[hh*512 + 256 + lane*4];
        #pragma unroll
        for (int j = 0; j < 8; ++j)
          acc[j] = wr[j][0]*xv0.x + wr[j][1]*xv0.y + wr[j][2]*xv0.z + wr[j][3]*xv0.w +
                   wr[j][4]*xv1.x + wr[j][5]*xv1.y + wr[j][6]*xv1.z + wr[j][7]*xv1.w;
      }
      #pragma unroll
      for (int j = 0; j < 8; ++j)
        #pragma unroll
        for (int msk = 1; msk < 64; msk <<= 1)
          acc[j] += __shfl_xor(acc[j], msk, 64);
      if (lane == 0) {
        #pragma unroll
        for (int j = 0; j < 8; ++j) gbuf[w][j] = acc[j];
      }
      __syncthreads();
      if (tid < 8) {
        const int j = tid;
        float iv = sigmoid_f(gbuf[0][j] + gbuf[1][j] + g0v[0]);
        float fv = sigmoid_f(gbuf[2][j] + gbuf[3][j] + g0v[1]);
        float gv = tanhf   (gbuf[4][j] + gbuf[5][j] + g0v[2]);
        float ov = sigmoid_f(gbuf[6][j] + gbuf[7][j] + g0v[3]);
        float c  = fv * cbuf[j] + iv * gv;
        cbuf[j]  = c;
        float h  = ov * tanhf(c);
        gastore(&h0h[(size_t)(t+1)*H_DIM + jbase + j], h);
        if (t == T_STEPS - 1) { out_hc[jbase + j] = h; out_hc[2048 + jbase + j] = c; }
      }
    }
  } else {
    // ---- L1: K=2048 concat [y[t]; h1[t-1]]; wave covers 1024 k; 128 wVGPR ----
    float wr[8][16];
    {
      const float* base = hh ? Whh1 : Wih1;
      #pragma unroll
      for (int j = 0; j < 8; ++j) {
        const float* p = base + (size_t)(g*1024 + jbase + j) * 1024 + lane*4;
        #pragma unroll
        for (int q = 0; q < 4; ++q) {
          float4 v = *(const float4*)(p + q*256);
          wr[j][q*4+0]=v.x; wr[j][q*4+1]=v.y; wr[j][q*4+2]=v.z; wr[j][q*4+3]=v.w;
        }
      }
    }
    float bi1[4] = {0.f,0.f,0.f,0.f};
    if (tid < 8) {
      int j = jbase + tid;
      #pragma unroll
      for (int q = 0; q < 4; ++q) bi1[q] = bih1[q*1024 + j] + bhh1[q*1024 + j];
    }
    __syncthreads();
    for (int t = 0; t < T_STEPS; ++t) {
      { // poll+stage [h0h[t+1] ; h1h[t]] — 512 threads x 4 words
        const float* p = (tid < 256) ? (h0h + (size_t)(t+1)*H_DIM + tid*4)
                                     : (h1h + (size_t)t*H_DIM + (tid-256)*4);
        float4 v; int sp = 0;
        for (;;) {
          v.x = gaload(p+0); v.y = gaload(p+1); v.z = gaload(p+2); v.w = gaload(p+3);
          if (__float_as_uint(v.x) != SENTU && __float_as_uint(v.y) != SENTU &&
              __float_as_uint(v.z) != SENTU && __float_as_uint(v.w) != SENTU) break;
          if (++sp > 16) __builtin_amdgcn_s_sleep(1);
          if (sp > SPIN_CAP) break;
        }
        *(float4*)&hbuf[tid*4] = v;
      }
      __syncthreads();
      float acc[8];
      {
        float4 xv[4];
        #pragma unroll
        for (int q = 0; q < 4; ++q)
          xv[q] = *(const float4*)&hbuf[hh*1024 + q*256 + lane*4];
        #pragma unroll
        for (int j = 0; j < 8; ++j) {
          float s = 0.f;
          #pragma unroll
          for (int q = 0; q < 4; ++q)
            s += wr[j][q*4+0]*xv[q].x + wr[j][q*4+1]*xv[q].y +
                 wr[j][q*4+2]*xv[q].z + wr[j][q*4+3]*xv[q].w;
          acc[j] = s;
        }
      }
      #pragma unroll
      for (int j = 0; j < 8; ++j)
        #pragma unroll
        for (int msk = 1; msk < 64; msk <<= 1)
          acc[j] += __shfl_xor(acc[j], msk, 64);
      if (lane == 0) {
        #pragma unroll
        for (int j = 0; j < 8; ++j) gbuf[w][j] = acc[j];
      }
      __syncthreads();
      if (tid < 8) {
        const int j = tid;
        float iv = sigmoid_f(gbuf[0][j] + gbuf[1][j] + bi1[0]);
        float fv = sigmoid_f(gbuf[2][j] + gbuf[3][j] + bi1[1]);
        float gv = tanhf   (gbuf[4][j] + gbuf[5][j] + bi1[2]);
        float ov = sigmoid_f(gbuf[6][j] + gbuf[7][j] + bi1[3]);
        float c  = fv * cbuf[j] + iv * gv;
        cbuf[j]  = c;
        float h  = ov * tanhf(c);
        gastore(&h1h[(size_t)(t+1)*H_DIM + jbase + j], h);
        h1out[(size_t)t*H_DIM + jbase + j] = h;
        if (t == T_STEPS - 1) { out_hc[1024 + jbase + j] = h; out_hc[3072 + jbase + j] = c; }
      }
    }
  }
}

// ---------------------------------------------------------------------------
extern "C" void kernel_launch(void* const* d_in, const int* in_sizes, int n_in,
                              void* d_out, int out_size, void* d_ws, size_t ws_size,
                              hipStream_t stream)
{
  (void)in_sizes; (void)n_in; (void)out_size; (void)ws_size;
  const int*   x    = (const int*)  d_in[0];
  const float* emb  = (const float*)d_in[1];
  const float* W_ih = (const float*)d_in[2];   // (2, 4096, 1024)
  const float* W_hh = (const float*)d_in[3];
  const float* b_ih = (const float*)d_in[4];   // (2, 4096)
  const float* b_hh = (const float*)d_in[5];
  const float* W_fc = (const float*)d_in[6];   // (32000, 1024)
  const float* b_fc = (const float*)d_in[7];
  float* out = (float*)d_out;                  // scores(512x32000) | h(2x1024) | c(2x1024)

  // workspace layout (floats); ~14.5 MB total
  float* ws    = (float*)d_ws;
  float* G0    = ws;                                         // 512*4096
  float* h0h   = G0   + (size_t)T_STEPS * 4096;              // 513*1024
  float* h1h   = h0h  + (size_t)(T_STEPS + 1) * H_DIM;       // 513*1024
  float* h1out = h1h  + (size_t)(T_STEPS + 1) * H_DIM;       // 512*1024
  int*   xmap  = (int*)(h1out + (size_t)T_STEPS * H_DIM);    // 512 ints

  init_ws_k<<<128, 256, 0, stream>>>(x, h0h, h1h, xmap);

  // G0[t,:] = W_ih0 @ emb[x_t] + b_ih0 + b_hh0   (512 x 4096)
  gemm_atb_k<<<dim3(4096 / BN, T_STEPS / BM), 256, 0, stream>>>(
      nullptr, emb, xmap, W_ih, b_ih, b_hh, G0, T_STEPS, 4096, 1024);

  // sequential scan (two layer domains, sentinel signaling, no spill)
  lstm_seq_k<<<256, 512, 0, stream>>>(
      W_hh, W_ih + (size_t)4096 * 1024, W_hh + (size_t)4096 * 1024,
      b_ih + 4096, b_hh + 4096, G0, h0h, h1h, h1out,
      out + (size_t)T_STEPS * VOCAB);

  // scores = outs @ W_fc^T + b_fc
  gemm_atb_k<<<dim3(VOCAB / BN, T_STEPS / BM), 256, 0, stream>>>(
      h1out, nullptr, nullptr, W_fc, b_fc, nullptr, out, T_STEPS, VOCAB, 1024);
}